// Round 12
// baseline (132.513 us; speedup 1.0000x reference)
//
#include <hip/hip_runtime.h>
#include <hip/hip_bf16.h>

typedef __attribute__((ext_vector_type(4))) float f32x4;
typedef __attribute__((ext_vector_type(8))) short s16x8;

// HW packed f32->bf16 (RTNE), 1 instr per 2 elements.
__device__ inline unsigned cvtpk(float a, float b) {
  unsigned r;
  asm("v_cvt_pk_bf16_f32 %0, %1, %2" : "=v"(r) : "v"(a), "v"(b));
  return r;
}
__device__ inline s16x8 pack8(f32x4 a, f32x4 b) {
  union { unsigned u[4]; s16x8 v; } x;
  x.u[0] = cvtpk(a[0], a[1]); x.u[1] = cvtpk(a[2], a[3]);
  x.u[2] = cvtpk(b[0], b[1]); x.u[3] = cvtpk(b[2], b[3]);
  return x.v;
}

// Explicit LDS ordering fence (R3 lesson: same-wave LDS write->read and
// read->write are NOT implicitly ordered; always drain lgkmcnt).
__device__ inline void lds_fence() {
  asm volatile("s_waitcnt lgkmcnt(0)" ::: "memory");
  __builtin_amdgcn_sched_barrier(0);
}

// R12: the REAL occupancy test. R6's launch_bounds(256,3) was confounded —
// dbuf LDS (64KB/WG) pinned residency at 2 WGs/CU no matter the VGPR cap.
// Here: SINGLE-buffer staging (8KB/wave, 32KB/WG) -> min(LDS:5, VGPR:3) =
// 3 WGs/CU (+50% streams). Costs one extra WAR fence per slab (~150cy/8KB
// drain). Everything else = R5: nt stores (R8: -14%), plain loads (R10),
// 2-deep prefetch, cvt_pk, bias-in-acc, 2048 WGs.
__global__ __launch_bounds__(256, 3)
void sparse_deconv_kernel(const float* __restrict__ in, const float* __restrict__ mask,
                          const float* __restrict__ kern, const float* __restrict__ bias,
                          float* __restrict__ out) {
  __shared__ float lds[4][2048];           // 8KB per wave, wave-private, single-buf
  const int tid = threadIdx.x;
  const int w  = tid >> 6;
  const int l  = tid & 63;
  const int lm = l & 15;
  const int lg = l >> 4;
  const int r  = w & 1;                    // input row parity within slab
  const int ky = w >> 1;                   // output row parity

  // Weights for this ky: mt = ky*8 + kx*4 + ft (kernel flat [256][64])
  s16x8 wf[8][2];
#pragma unroll
  for (int m2 = 0; m2 < 8; ++m2) {
#pragma unroll
    for (int kf = 0; kf < 2; ++kf) {
      const float* p = kern + (((ky * 8 + m2) * 16 + lm) * 64 + kf * 32 + lg * 8);
      wf[m2][kf] = pack8(*(const f32x4*)p, *(const f32x4*)(p + 4));
    }
  }
  f32x4 bv[4];
#pragma unroll
  for (int ft = 0; ft < 4; ++ft)
    bv[ft] = *(const f32x4*)(bias + ft * 16 + lg * 4);

  const int b  = blockIdx.x;   // 0..2047
  const int n  = b >> 8;
  const int by = (b >> 4) & 15;
  const int bx = b & 15;

  // per-block mask max (redundant per wave; no block barriers anywhere)
  const float* mp = mask + ((n * 256 + by * 16) * 256 + bx * 16);
  float mv = 0.0f;
#pragma unroll
  for (int i = 0; i < 4; ++i) {
    const int idx = i * 64 + l;
    mv = fmaxf(mv, mp[(idx >> 4) * 256 + (idx & 15)]);
  }
#pragma unroll
  for (int off = 32; off; off >>= 1)
    mv = fmaxf(mv, __shfl_xor(mv, off));
  const bool active = mv > 0.5f;

  const float* ibase = in + (((n * 256 + by * 16) * 256) + bx * 16 + lm) * 64 + lg * 8;
  float* oorigin = out + (((size_t)(n * 512 + by * 32)) * 512 + bx * 32) * 64;
  const int oyw = 2 * r + ky;
  float* LB = &lds[w][0];

  if (active) {
    f32x4 tb[2][4];   // two rotating row buffers (fully unrolled -> static idx)
#pragma unroll
    for (int q = 0; q < 2; ++q) {
      const float* p = ibase + (2 * q + r) * (256 * 64);
      tb[q][0] = *(const f32x4*)p;        tb[q][1] = *(const f32x4*)(p + 4);
      tb[q][2] = *(const f32x4*)(p + 32); tb[q][3] = *(const f32x4*)(p + 36);
    }
#pragma unroll
    for (int s = 0; s < 8; ++s) {
      const int bsel = s & 1;
      s16x8 xf0 = pack8(tb[bsel][0], tb[bsel][1]);
      s16x8 xf1 = pack8(tb[bsel][2], tb[bsel][3]);
      if (s < 6) {   // prefetch 2 slabs ahead into the buffer just consumed
        const float* p = ibase + (2 * (s + 2) + r) * (256 * 64);
        tb[bsel][0] = *(const f32x4*)p;        tb[bsel][1] = *(const f32x4*)(p + 4);
        tb[bsel][2] = *(const f32x4*)(p + 32); tb[bsel][3] = *(const f32x4*)(p + 36);
      }
      // WAR: previous slab's readback must drain before overwriting the buffer
      if (s > 0) lds_fence();
#pragma unroll
      for (int kx = 0; kx < 2; ++kx) {
#pragma unroll
        for (int ft = 0; ft < 4; ++ft) {
          f32x4 acc = bv[ft];
          acc = __builtin_amdgcn_mfma_f32_16x16x32_bf16(wf[kx * 4 + ft][0], xf0, acc, 0, 0, 0);
          acc = __builtin_amdgcn_mfma_f32_16x16x32_bf16(wf[kx * 4 + ft][1], xf1, acc, 0, 0, 0);
          const int p  = 2 * lm + kx;                // pixel 0..31
          const int sl = (4 * ft + lg + p) & 15;     // rotated fslot
          *(f32x4*)(LB + p * 64 + sl * 4) = acc;
        }
      }
      lds_fence();   // RAW: staging writes complete before readback

      const int oy = 4 * s + oyw;
      float* orow = oorigin + (size_t)oy * (512 * 64) + l * 4;
#pragma unroll
      for (int rc = 0; rc < 8; ++rc) {
        const int p  = rc * 4 + lg;
        const int sl = (lm + p) & 15;
        f32x4 v = *(const f32x4*)(LB + p * 64 + sl * 4);
        __builtin_nontemporal_store(v, (f32x4*)(orow + rc * 256));  // 1KB/instr
      }
    }
  } else {
    const f32x4 z = {0.f, 0.f, 0.f, 0.f};
#pragma unroll
    for (int i = 0; i < 8; ++i) {
      float* orow = oorigin + (size_t)(w * 8 + i) * (512 * 64) + l * 4;
#pragma unroll
      for (int rc = 0; rc < 8; ++rc)
        __builtin_nontemporal_store(z, (f32x4*)(orow + rc * 256));
    }
  }
}

extern "C" void kernel_launch(void* const* d_in, const int* in_sizes, int n_in,
                              void* d_out, int out_size, void* d_ws, size_t ws_size,
                              hipStream_t stream) {
  const float* in   = (const float*)d_in[0];
  const float* mask = (const float*)d_in[1];
  const float* kern = (const float*)d_in[2];
  const float* bias = (const float*)d_in[3];
  float* out = (float*)d_out;
  dim3 grid(2048), block(256);
  hipLaunchKernelGGL(sparse_deconv_kernel, grid, block, 0, stream,
                     in, mask, kern, bias, out);
}

// Round 13
// 127.583 us; speedup vs baseline: 1.0386x; 1.0386x over previous
//
#include <hip/hip_runtime.h>
#include <hip/hip_bf16.h>

typedef __attribute__((ext_vector_type(4))) float f32x4;
typedef __attribute__((ext_vector_type(8))) short s16x8;

// HW packed f32->bf16 (RTNE), 1 instr per 2 elements.
__device__ inline unsigned cvtpk(float a, float b) {
  unsigned r;
  asm("v_cvt_pk_bf16_f32 %0, %1, %2" : "=v"(r) : "v"(a), "v"(b));
  return r;
}
__device__ inline s16x8 pack8(f32x4 a, f32x4 b) {
  union { unsigned u[4]; s16x8 v; } x;
  x.u[0] = cvtpk(a[0], a[1]); x.u[1] = cvtpk(a[2], a[3]);
  x.u[2] = cvtpk(b[0], b[1]); x.u[3] = cvtpk(b[2], b[3]);
  return x.v;
}

// Explicit LDS RAW fence (R3 lesson: wave-private LDS write->read is NOT
// implicitly ordered; compiler can't prove rotated-slot aliasing).
__device__ inline void lds_fence() {
  asm volatile("s_waitcnt lgkmcnt(0)" ::: "memory");
  __builtin_amdgcn_sched_barrier(0);
}

// FINAL = R5 (best measured: 130.8 us, 84% of the 6.29 TB/s copy ceiling on a
// 4:1 W:R mixed stream). Proven levers: LDS-transpose store contiguity
// (1KB/instr), dbuf staging + 2-deep input prefetch + cvt_pk pipeline, and
// nontemporal STORES only (R8 A/B: -14%; nt loads hurt, R10: L2 serves the
// ky-partner's duplicate input reads). Falsified: occupancy (R12 clean test),
// input dedup (R7), persistent grid (R9), speculative prologue (R11).
// Residual ~20% gap to pure-copy = HBM read<->write turnaround (not HIP-
// controllable); compute ~5% busy -> memory-bound at achievable mixed BW.
__global__ __launch_bounds__(256, 2)
void sparse_deconv_kernel(const float* __restrict__ in, const float* __restrict__ mask,
                          const float* __restrict__ kern, const float* __restrict__ bias,
                          float* __restrict__ out) {
  __shared__ float lds[4][2][2048];        // 16KB per wave, wave-private, dbuf
  const int tid = threadIdx.x;
  const int w  = tid >> 6;
  const int l  = tid & 63;
  const int lm = l & 15;
  const int lg = l >> 4;
  const int r  = w & 1;                    // input row parity within slab
  const int ky = w >> 1;                   // output row parity

  // Weights for this ky: mt = ky*8 + kx*4 + ft (kernel flat [256][64])
  s16x8 wf[8][2];
#pragma unroll
  for (int m2 = 0; m2 < 8; ++m2) {
#pragma unroll
    for (int kf = 0; kf < 2; ++kf) {
      const float* p = kern + (((ky * 8 + m2) * 16 + lm) * 64 + kf * 32 + lg * 8);
      wf[m2][kf] = pack8(*(const f32x4*)p, *(const f32x4*)(p + 4));
    }
  }
  f32x4 bv[4];
#pragma unroll
  for (int ft = 0; ft < 4; ++ft)
    bv[ft] = *(const f32x4*)(bias + ft * 16 + lg * 4);

  const int b  = blockIdx.x;   // 0..2047
  const int n  = b >> 8;
  const int by = (b >> 4) & 15;
  const int bx = b & 15;

  // per-block mask max (redundant per wave; no block barriers anywhere)
  const float* mp = mask + ((n * 256 + by * 16) * 256 + bx * 16);
  float mv = 0.0f;
#pragma unroll
  for (int i = 0; i < 4; ++i) {
    const int idx = i * 64 + l;
    mv = fmaxf(mv, mp[(idx >> 4) * 256 + (idx & 15)]);
  }
#pragma unroll
  for (int off = 32; off; off >>= 1)
    mv = fmaxf(mv, __shfl_xor(mv, off));
  const bool active = mv > 0.5f;

  const float* ibase = in + (((n * 256 + by * 16) * 256) + bx * 16 + lm) * 64 + lg * 8;
  float* oorigin = out + (((size_t)(n * 512 + by * 32)) * 512 + bx * 32) * 64;
  const int oyw = 2 * r + ky;

  if (active) {
    f32x4 tb[2][4];   // two rotating row buffers (fully unrolled -> static idx)
#pragma unroll
    for (int q = 0; q < 2; ++q) {
      const float* p = ibase + (2 * q + r) * (256 * 64);
      tb[q][0] = *(const f32x4*)p;        tb[q][1] = *(const f32x4*)(p + 4);
      tb[q][2] = *(const f32x4*)(p + 32); tb[q][3] = *(const f32x4*)(p + 36);
    }
#pragma unroll
    for (int s = 0; s < 8; ++s) {
      const int bsel = s & 1;
      s16x8 xf0 = pack8(tb[bsel][0], tb[bsel][1]);
      s16x8 xf1 = pack8(tb[bsel][2], tb[bsel][3]);
      if (s < 6) {   // prefetch 2 slabs ahead into the buffer just consumed
        const float* p = ibase + (2 * (s + 2) + r) * (256 * 64);
        tb[bsel][0] = *(const f32x4*)p;        tb[bsel][1] = *(const f32x4*)(p + 4);
        tb[bsel][2] = *(const f32x4*)(p + 32); tb[bsel][3] = *(const f32x4*)(p + 36);
      }
      float* LB = &lds[w][bsel][0];
#pragma unroll
      for (int kx = 0; kx < 2; ++kx) {
#pragma unroll
        for (int ft = 0; ft < 4; ++ft) {
          f32x4 acc = bv[ft];
          acc = __builtin_amdgcn_mfma_f32_16x16x32_bf16(wf[kx * 4 + ft][0], xf0, acc, 0, 0, 0);
          acc = __builtin_amdgcn_mfma_f32_16x16x32_bf16(wf[kx * 4 + ft][1], xf1, acc, 0, 0, 0);
          const int p  = 2 * lm + kx;                // pixel 0..31
          const int sl = (4 * ft + lg + p) & 15;     // rotated fslot
          *(f32x4*)(LB + p * 64 + sl * 4) = acc;
        }
      }
      lds_fence();   // RAW: this slab's staging writes complete before readback

      const int oy = 4 * s + oyw;
      float* orow = oorigin + (size_t)oy * (512 * 64) + l * 4;
#pragma unroll
      for (int rc = 0; rc < 8; ++rc) {
        const int p  = rc * 4 + lg;
        const int sl = (lm + p) & 15;
        f32x4 v = *(const f32x4*)(LB + p * 64 + sl * 4);
        __builtin_nontemporal_store(v, (f32x4*)(orow + rc * 256));  // 1KB/instr
      }
    }
  } else {
    const f32x4 z = {0.f, 0.f, 0.f, 0.f};
#pragma unroll
    for (int i = 0; i < 8; ++i) {
      float* orow = oorigin + (size_t)(w * 8 + i) * (512 * 64) + l * 4;
#pragma unroll
      for (int rc = 0; rc < 8; ++rc)
        __builtin_nontemporal_store(z, (f32x4*)(orow + rc * 256));
    }
  }
}

extern "C" void kernel_launch(void* const* d_in, const int* in_sizes, int n_in,
                              void* d_out, int out_size, void* d_ws, size_t ws_size,
                              hipStream_t stream) {
  const float* in   = (const float*)d_in[0];
  const float* mask = (const float*)d_in[1];
  const float* kern = (const float*)d_in[2];
  const float* bias = (const float*)d_in[3];
  float* out = (float*)d_out;
  dim3 grid(2048), block(256);
  hipLaunchKernelGGL(sparse_deconv_kernel, grid, block, 0, stream,
                     in, mask, kern, bias, out);
}